// Round 1
// baseline (927.091 us; speedup 1.0000x reference)
//
#include <hip/hip_runtime.h>
#include <cstddef>

#define WLEN 16384
#define SCALEQ 0.17677669529663687f   // 32^-0.5

// ws float offsets
#define WS_CTX 0         // 16*4*32*32 = 65536 floats (zeroed)
#define WS_DEN 65536     // 16*4*32    = 2048  floats (zeroed)
#define WS_WT  67584     // W_qkv^T [c][384] = 49152 floats
#define WS_WOT 116736    // W_out^T [c][128] = 16384 floats
#define WS_CBT 133120    // C_b^T   [b][hd][o] = 16*128*128 = 262144 floats

#define FMA4x4(A, wv, xv) \
  A[0][0] += wv.x*xv.x; A[0][1] += wv.x*xv.y; A[0][2] += wv.x*xv.z; A[0][3] += wv.x*xv.w; \
  A[1][0] += wv.y*xv.x; A[1][1] += wv.y*xv.y; A[1][2] += wv.y*xv.z; A[1][3] += wv.y*xv.w; \
  A[2][0] += wv.z*xv.x; A[2][1] += wv.z*xv.y; A[2][2] += wv.z*xv.z; A[2][3] += wv.z*xv.w; \
  A[3][0] += wv.w*xv.x; A[3][1] += wv.w*xv.y; A[3][2] += wv.w*xv.z; A[3][3] += wv.w*xv.w;

// K0: transpose W_qkv (384x128 -> [c][384]) and W_out (128x128 -> [c][128])
__global__ __launch_bounds__(256) void k0_transpose(
    const float* __restrict__ Wqkv, const float* __restrict__ Wout,
    float* __restrict__ wt, float* __restrict__ wot) {
  int idx = blockIdx.x * 256 + threadIdx.x;
  if (idx < 49152) {
    int c = idx / 384, r = idx - c * 384;
    wt[idx] = Wqkv[r * 128 + c];
  } else if (idx < 65536) {
    int j = idx - 49152;
    int c = j >> 7, o = j & 127;
    wot[j] = Wout[o * 128 + c];
  }
}

// K1: per (chunk, h, b): k/v projection + exp(k) + unnormalized context & denom
// block = 256 threads, chunk = 512 positions, subtile = 64 positions
__global__ __launch_bounds__(256) void k1_ctx(
    const float* __restrict__ x, const float* __restrict__ wt,
    float* __restrict__ ctx, float* __restrict__ den) {
  __shared__ __align__(16) float xs[128][64];   // 32 KB
  __shared__ __align__(16) float eks[64][36];   // 9 KB (pad 36: 144B rows, 16B-aligned)
  __shared__ __align__(16) float vs[64][36];    // 9 KB
  const int tid = threadIdx.x;
  const int chunk = blockIdx.x, h = blockIdx.y, b = blockIdx.z;
  const int pg = tid & 15;        // position group (4 pos)
  const int rg = tid >> 4;        // row group (4 rows); rg<8 -> k rows, else v rows
  const int r0 = rg * 4;
  const int colbase = (r0 < 32) ? (128 + h * 32 + r0) : (256 + h * 32 + (r0 - 32));
  const int dd = tid >> 3;        // ctx: d index 0..31
  const int eg = tid & 7;         // ctx: e group (4 e's)
  float ctx_acc[4] = {0.f, 0.f, 0.f, 0.f};
  float den_acc = 0.f;
  const float* xb = x + (size_t)b * 128 * WLEN;
  const int nb = chunk * 512;

  for (int s = 0; s < 8; ++s) {
    const int n0 = nb + s * 64;
    __syncthreads();
    // stage x tile [128 c][64 p]
    for (int i = tid; i < 2048; i += 256) {
      int c = i >> 4, p4 = i & 15;
      ((float4*)xs[c])[p4] = ((const float4*)(xb + (size_t)c * WLEN + n0))[p4];
    }
    __syncthreads();
    // projection: 4 rows x 4 positions per thread
    float acc[4][4] = {{0.f,0.f,0.f,0.f},{0.f,0.f,0.f,0.f},{0.f,0.f,0.f,0.f},{0.f,0.f,0.f,0.f}};
    #pragma unroll 4
    for (int c = 0; c < 128; ++c) {
      float4 xv = ((const float4*)xs[c])[pg];
      float4 wv = *((const float4*)(wt + c * 384 + colbase));
      FMA4x4(acc, wv, xv)
    }
    const int p0 = pg * 4;
    if (rg < 8) {
      #pragma unroll
      for (int j = 0; j < 4; ++j)
        #pragma unroll
        for (int i = 0; i < 4; ++i)
          eks[p0 + i][r0 + j] = __expf(acc[j][i]);
    } else {
      #pragma unroll
      for (int j = 0; j < 4; ++j)
        #pragma unroll
        for (int i = 0; i < 4; ++i)
          vs[p0 + i][(r0 - 32) + j] = acc[j][i];
    }
    __syncthreads();
    // context accumulation: thread owns (d=dd, e=eg*4..eg*4+3)
    #pragma unroll 4
    for (int p = 0; p < 64; ++p) {
      float ek = eks[p][dd];
      float4 vv = ((const float4*)vs[p])[eg];
      ctx_acc[0] += ek * vv.x; ctx_acc[1] += ek * vv.y;
      ctx_acc[2] += ek * vv.z; ctx_acc[3] += ek * vv.w;
    }
    if (tid < 32) {
      #pragma unroll 4
      for (int p = 0; p < 64; ++p) den_acc += eks[p][tid];
    }
  }
  const int cbase = ((b * 4 + h) * 32 + dd) * 32 + eg * 4;
  atomicAdd(&ctx[cbase + 0], ctx_acc[0]);
  atomicAdd(&ctx[cbase + 1], ctx_acc[1]);
  atomicAdd(&ctx[cbase + 2], ctx_acc[2]);
  atomicAdd(&ctx[cbase + 3], ctx_acc[3]);
  if (tid < 32) atomicAdd(&den[(b * 4 + h) * 32 + tid], den_acc);
}

// K2: C_b^T[hd][o] = sum_e Wout[o][h*32+e] * ctx[b,h][d][e] / (den[b,h,d]*W)
__global__ __launch_bounds__(256) void k2_cbt(
    const float* __restrict__ ctx, const float* __restrict__ den,
    const float* __restrict__ wot, float* __restrict__ cbt) {
  __shared__ float nc[4096];
  const int b = blockIdx.x, tid = threadIdx.x;
  for (int i = tid; i < 4096; i += 256) {
    nc[i] = ctx[b * 4096 + i] / (den[b * 128 + (i >> 5)] * 16384.0f);
  }
  __syncthreads();
  for (int k = 0; k < 64; ++k) {
    int idx = tid + 256 * k;
    int hd = idx >> 7, o = idx & 127;
    int h = hd >> 5;
    float acc = 0.f;
    #pragma unroll 8
    for (int e = 0; e < 32; ++e)
      acc += nc[hd * 32 + e] * wot[(h * 32 + e) * 128 + o];
    cbt[b * 16384 + idx] = acc;
  }
}

// K3: per (tile of 128 positions, b): q-proj -> per-head softmax*SCALE -> C_b apply
//     -> +b_out -> channel LayerNorm -> store
__global__ __launch_bounds__(256) void k3_out(
    const float* __restrict__ x, const float* __restrict__ wt,
    const float* __restrict__ cbt, const float* __restrict__ b_out,
    const float* __restrict__ gamma, const float* __restrict__ beta,
    float* __restrict__ out) {
  __shared__ __align__(16) float qs[128][128];   // 64 KB exactly; reused for y
  const int tid = threadIdx.x;
  const int tile = blockIdx.x, b = blockIdx.y;
  const int n0 = tile * 128;
  const int dg = tid >> 5, pg = tid & 31;        // dg 0..7 (4 rows), pg 0..31 (4 pos)
  const float* xb = x + (size_t)b * 128 * WLEN;

  // phase 1: q_raw per head -> qs
  for (int h = 0; h < 4; ++h) {
    const int colb = h * 32 + dg * 4;
    float acc[4][4] = {{0.f,0.f,0.f,0.f},{0.f,0.f,0.f,0.f},{0.f,0.f,0.f,0.f},{0.f,0.f,0.f,0.f}};
    #pragma unroll 4
    for (int c = 0; c < 128; ++c) {
      float4 xv = ((const float4*)(xb + (size_t)c * WLEN + n0))[pg];
      float4 wv = *((const float4*)(wt + c * 384 + colb));
      FMA4x4(acc, wv, xv)
    }
    #pragma unroll
    for (int j = 0; j < 4; ++j)
      #pragma unroll
      for (int i = 0; i < 4; ++i)
        qs[h * 32 + dg * 4 + j][pg * 4 + i] = acc[j][i];
  }
  __syncthreads();
  // softmax over d (32) per (h, p), then * SCALE
  for (int k = 0; k < 2; ++k) {
    int idx = tid + 256 * k;
    int h = idx >> 7, p = idx & 127;
    float v[32];
    float m = -1e30f;
    #pragma unroll
    for (int d = 0; d < 32; ++d) { v[d] = qs[h * 32 + d][p]; m = fmaxf(m, v[d]); }
    float ssum = 0.f;
    #pragma unroll
    for (int d = 0; d < 32; ++d) { v[d] = __expf(v[d] - m); ssum += v[d]; }
    float sc = SCALEQ / ssum;
    #pragma unroll
    for (int d = 0; d < 32; ++d) qs[h * 32 + d][p] = v[d] * sc;
  }
  __syncthreads();
  // phase 2: y[o][p] = sum_hd C_b^T[hd][o] * q_sm[hd][p]; all 4 o-groups in regs
  float ya[4][4][4];
  #pragma unroll
  for (int og = 0; og < 4; ++og)
    #pragma unroll
    for (int j = 0; j < 4; ++j)
      #pragma unroll
      for (int i = 0; i < 4; ++i) ya[og][j][i] = 0.f;
  const float* cb = cbt + b * 16384;
  #pragma unroll 2
  for (int hd = 0; hd < 128; ++hd) {
    float4 qv = ((const float4*)qs[hd])[pg];
    #pragma unroll
    for (int og = 0; og < 4; ++og) {
      float4 cv = *((const float4*)(cb + hd * 128 + og * 32 + dg * 4));
      FMA4x4(ya[og], cv, qv)
    }
  }
  __syncthreads();   // all reads of qs done; safe to overwrite with y
  #pragma unroll
  for (int og = 0; og < 4; ++og) {
    #pragma unroll
    for (int j = 0; j < 4; ++j) {
      int o = og * 32 + dg * 4 + j;
      float bo = b_out[o];
      #pragma unroll
      for (int i = 0; i < 4; ++i)
        qs[o][pg * 4 + i] = ya[og][j][i] + bo;
    }
  }
  __syncthreads();
  // LayerNorm over 128 channels, one thread per column
  if (tid < 128) {
    const int p = tid;
    float ssum = 0.f, ssq = 0.f;
    for (int c2 = 0; c2 < 128; ++c2) { float v = qs[c2][p]; ssum += v; ssq += v * v; }
    float mean = ssum * (1.0f / 128.0f);
    float var = ssq * (1.0f / 128.0f) - mean * mean;
    float inv = rsqrtf(var + 1e-5f);
    float* ob = out + (size_t)b * 128 * WLEN + n0 + p;
    for (int c2 = 0; c2 < 128; ++c2) {
      ob[(size_t)c2 * WLEN] = (qs[c2][p] - mean) * inv * gamma[c2] + beta[c2];
    }
  }
}

extern "C" void kernel_launch(void* const* d_in, const int* in_sizes, int n_in,
                              void* d_out, int out_size, void* d_ws, size_t ws_size,
                              hipStream_t stream) {
  const float* x    = (const float*)d_in[0];
  const float* Wqkv = (const float*)d_in[1];
  const float* Wout = (const float*)d_in[2];
  const float* bo   = (const float*)d_in[3];
  const float* gam  = (const float*)d_in[4];
  const float* bet  = (const float*)d_in[5];
  float* out = (float*)d_out;
  float* ws  = (float*)d_ws;

  // zero the atomic accumulators (ctx + den)
  hipMemsetAsync(ws, 0, (65536 + 2048) * sizeof(float), stream);

  hipLaunchKernelGGL(k0_transpose, dim3(256), dim3(256), 0, stream,
                     Wqkv, Wout, ws + WS_WT, ws + WS_WOT);
  hipLaunchKernelGGL(k1_ctx, dim3(32, 4, 16), dim3(256), 0, stream,
                     x, ws + WS_WT, ws + WS_CTX, ws + WS_DEN);
  hipLaunchKernelGGL(k2_cbt, dim3(16), dim3(256), 0, stream,
                     ws + WS_CTX, ws + WS_DEN, ws + WS_WOT, ws + WS_CBT);
  hipLaunchKernelGGL(k3_out, dim3(128, 16), dim3(256), 0, stream,
                     x, ws + WS_WT, ws + WS_CBT, bo, gam, bet, out);
}

// Round 2
// 304.655 us; speedup vs baseline: 3.0431x; 3.0431x over previous
//
#include <hip/hip_runtime.h>
#include <cstddef>

#define WLEN 16384
#define SCALEQ 0.17677669529663687f       // 32^-0.5
#define CB_SCALE 16777216.0f              // 2^24 (keeps C_b out of fp16 subnormals)
#define CB_INV   5.9604644775390625e-08f  // 2^-24

typedef _Float16 half8 __attribute__((ext_vector_type(8)));
typedef _Float16 half4 __attribute__((ext_vector_type(4)));
typedef _Float16 half2v __attribute__((ext_vector_type(2)));
typedef float float4v __attribute__((ext_vector_type(4)));

// ws float offsets
#define WS_CTX 0         // 16*4*32*32 = 65536 floats (zeroed)
#define WS_DEN 65536     // 16*4*32    = 2048  floats (zeroed)
#define WS_WH  67584     // Wqkv fp16 [384][128] = 49152 halfs = 24576 floats
#define WS_CB  92160     // C_b  fp16 [16][128][128] = 262144 halfs = 131072 floats

#define MFMA16(a, b, c) __builtin_amdgcn_mfma_f32_16x16x32_f16(a, b, c, 0, 0, 0)

// K0: elementwise fp32 -> fp16 of W_qkv (layout unchanged: [384 rows][128 k])
__global__ __launch_bounds__(256) void k0_prep(const float* __restrict__ Wqkv,
                                               float* __restrict__ ws) {
  int idx = blockIdx.x * 256 + threadIdx.x;
  _Float16* Wh = (_Float16*)(ws + WS_WH);
  if (idx < 49152) Wh[idx] = (_Float16)Wqkv[idx];
}

// KA: k/v projection (f16 MFMA) + exp(k) + ctx = ek @ v^T (f16 MFMA) + den
// grid (32 chunks, 16 b), block 256 = 4 waves, wave w <-> head w
// chunk = 512 positions, subtile = 32 positions
__global__ __launch_bounds__(256, 2) void ka_ctx(
    const float* __restrict__ x, float* __restrict__ ws) {
  __shared__ __align__(16) _Float16 xh[32 * 136];     // x^T tile [n][c], pad 136
  __shared__ __align__(16) _Float16 ekl[4 * 32 * 40]; // per-wave [d][n], pad 40
  __shared__ __align__(16) _Float16 vl[4 * 32 * 40];  // per-wave [e][n], pad 40
  const int tid = threadIdx.x;
  const int lane = tid & 63, wv = tid >> 6;
  const int l15 = lane & 15, quad = lane >> 4;
  const int b = blockIdx.y, chunk = blockIdx.x;
  const _Float16* Wh = (const _Float16*)(ws + WS_WH);
  float* ctx = ws + WS_CTX;
  float* den = ws + WS_DEN;
  const float* xb = x + (size_t)b * 128 * WLEN;

  // weights stationary: 4 mtiles (mt 0,1 = k rows; 2,3 = v rows) x 4 ksteps
  half8 afr[4][4];
  #pragma unroll
  for (int mt = 0; mt < 4; ++mt) {
    int row = (mt < 2) ? (128 + 32 * wv + mt * 16 + l15)
                       : (256 + 32 * wv + (mt - 2) * 16 + l15);
    #pragma unroll
    for (int ks = 0; ks < 4; ++ks)
      afr[mt][ks] = *(const half8*)(Wh + row * 128 + ks * 32 + quad * 8);
  }

  const float4v zero4 = {0.f, 0.f, 0.f, 0.f};
  float4v ctxa[2][2] = {zero4, zero4, zero4, zero4};
  float denr[8] = {0.f, 0.f, 0.f, 0.f, 0.f, 0.f, 0.f, 0.f};

  for (int s = 0; s < 16; ++s) {
    const int n0 = chunk * 512 + s * 32;
    __syncthreads();
    // stage x fp32 [c][n] -> fp16 transposed [n][c] (c-pairs -> half2 writes)
    #pragma unroll
    for (int it = 0; it < 2; ++it) {
      int idx = it * 256 + tid;
      int f = idx & 7, cp = idx >> 3;   // f: n-group (4n), cp: c-pair
      const float* p0 = xb + (size_t)(2 * cp) * WLEN + n0 + 4 * f;
      float4 a = *(const float4*)p0;
      float4 c = *(const float4*)(p0 + WLEN);
      float av[4] = {a.x, a.y, a.z, a.w};
      float cv[4] = {c.x, c.y, c.z, c.w};
      #pragma unroll
      for (int i = 0; i < 4; ++i) {
        half2v h; h[0] = (_Float16)av[i]; h[1] = (_Float16)cv[i];
        *(half2v*)&xh[(4 * f + i) * 136 + 2 * cp] = h;
      }
    }
    __syncthreads();
    // k/v projection: M=64 (wave rows), N=32, K=128
    float4v acc[4][2] = {zero4, zero4, zero4, zero4, zero4, zero4, zero4, zero4};
    #pragma unroll
    for (int ks = 0; ks < 4; ++ks) {
      half8 b0 = *(const half8*)&xh[l15 * 136 + ks * 32 + quad * 8];
      half8 b1 = *(const half8*)&xh[(16 + l15) * 136 + ks * 32 + quad * 8];
      #pragma unroll
      for (int mt = 0; mt < 4; ++mt) {
        acc[mt][0] = MFMA16(afr[mt][ks], b0, acc[mt][0]);
        acc[mt][1] = MFMA16(afr[mt][ks], b1, acc[mt][1]);
      }
    }
    // ek (with den partials) and v -> per-wave LDS [row][n]
    #pragma unroll
    for (int mt = 0; mt < 2; ++mt)
      #pragma unroll
      for (int nt = 0; nt < 2; ++nt)
        #pragma unroll
        for (int r = 0; r < 4; ++r) {
          float e = __expf(acc[mt][nt][r]);
          denr[mt * 4 + r] += e;
          ekl[(wv * 32 + mt * 16 + quad * 4 + r) * 40 + nt * 16 + l15] = (_Float16)e;
        }
    #pragma unroll
    for (int mt = 0; mt < 2; ++mt)
      #pragma unroll
      for (int nt = 0; nt < 2; ++nt)
        #pragma unroll
        for (int r = 0; r < 4; ++r)
          vl[(wv * 32 + mt * 16 + quad * 4 + r) * 40 + nt * 16 + l15] =
              (_Float16)acc[mt + 2][nt][r];
    // ctx += ek @ v^T : M=32 d, N=32 e, K=32 n (wave-private, no barrier needed)
    half8 ae0 = *(const half8*)&ekl[(wv * 32 + l15) * 40 + quad * 8];
    half8 ae1 = *(const half8*)&ekl[(wv * 32 + 16 + l15) * 40 + quad * 8];
    half8 bv0 = *(const half8*)&vl[(wv * 32 + l15) * 40 + quad * 8];
    half8 bv1 = *(const half8*)&vl[(wv * 32 + 16 + l15) * 40 + quad * 8];
    ctxa[0][0] = MFMA16(ae0, bv0, ctxa[0][0]);
    ctxa[0][1] = MFMA16(ae0, bv1, ctxa[0][1]);
    ctxa[1][0] = MFMA16(ae1, bv0, ctxa[1][0]);
    ctxa[1][1] = MFMA16(ae1, bv1, ctxa[1][1]);
  }
  // reduce to global
  #pragma unroll
  for (int dt = 0; dt < 2; ++dt)
    #pragma unroll
    for (int et = 0; et < 2; ++et)
      #pragma unroll
      for (int r = 0; r < 4; ++r)
        atomicAdd(&ctx[((b * 4 + wv) * 32 + dt * 16 + quad * 4 + r) * 32 +
                       et * 16 + l15],
                  ctxa[dt][et][r]);
  #pragma unroll
  for (int i = 0; i < 8; ++i) {
    float v = denr[i];
    v += __shfl_xor(v, 1, 64);
    v += __shfl_xor(v, 2, 64);
    v += __shfl_xor(v, 4, 64);
    v += __shfl_xor(v, 8, 64);
    if (l15 == 0)
      atomicAdd(&den[(b * 4 + wv) * 32 + (i >> 2) * 16 + quad * 4 + (i & 3)], v);
  }
}

// KB: C_b[o][hd] = sum_e Wout[o][h*32+e] * ctx[b,h][d][e]/(den*W), *2^24 -> fp16
__global__ __launch_bounds__(256) void kb_cb(
    const float* __restrict__ Wout, float* __restrict__ ws) {
  __shared__ __align__(16) float nc[4096];
  const int b = blockIdx.x, tid = threadIdx.x;
  const float* ctx = ws + WS_CTX;
  const float* den = ws + WS_DEN;
  _Float16* cb = (_Float16*)(ws + WS_CB) + b * 16384;
  for (int i = tid; i < 4096; i += 256)
    nc[i] = ctx[b * 4096 + i] / (den[b * 128 + (i >> 5)] * 16384.0f);
  __syncthreads();
  const int o = tid >> 1, dh = (tid & 1) * 16;
  for (int h = 0; h < 4; ++h) {
    float wrow[32];
    #pragma unroll
    for (int e4 = 0; e4 < 8; ++e4) {
      float4 w4 = *(const float4*)(Wout + o * 128 + h * 32 + e4 * 4);
      wrow[e4 * 4 + 0] = w4.x; wrow[e4 * 4 + 1] = w4.y;
      wrow[e4 * 4 + 2] = w4.z; wrow[e4 * 4 + 3] = w4.w;
    }
    for (int d = 0; d < 16; ++d) {
      const float* ncr = &nc[(h * 32 + dh + d) * 32];
      float acc = 0.f;
      #pragma unroll
      for (int e = 0; e < 32; ++e) acc += wrow[e] * ncr[e];
      cb[o * 128 + h * 32 + dh + d] = (_Float16)(acc * CB_SCALE);
    }
  }
}

// KC: q-proj MFMA -> per-head softmax (in regs) -> LDS roundtrip ->
//     C_b MFMA -> +b_out -> channel LayerNorm -> store
// grid (128 tiles, 16 b), block 256 = 4 waves, wave w <-> head w / o-strip w
__global__ __launch_bounds__(256, 2) void kc_out(
    const float* __restrict__ x, const float* __restrict__ wsc,
    const float* __restrict__ b_out, const float* __restrict__ gamma,
    const float* __restrict__ beta, float* __restrict__ out) {
  __shared__ __align__(16) _Float16 xh[128 * 136];  // x^T tile, reused as q_l[n][hd]
  __shared__ float ssum[4][128], ssq[4][128];
  __shared__ float smean[128], sinv[128];
  const int tid = threadIdx.x;
  const int lane = tid & 63, wv = tid >> 6;
  const int l15 = lane & 15, quad = lane >> 4;
  const int b = blockIdx.y, tile = blockIdx.x;
  const int n0 = tile * 128;
  const _Float16* Wh = (const _Float16*)(wsc + WS_WH);
  const _Float16* cb = (const _Float16*)(wsc + WS_CB) + b * 16384;
  const float* xb = x + (size_t)b * 128 * WLEN;
  const float4v zero4 = {0.f, 0.f, 0.f, 0.f};

  // phase-1 A-frags: q rows 32*wv .. +31 (head wv)
  half8 a1[2][4];
  #pragma unroll
  for (int mt = 0; mt < 2; ++mt)
    #pragma unroll
    for (int ks = 0; ks < 4; ++ks)
      a1[mt][ks] = *(const half8*)(Wh + (32 * wv + mt * 16 + l15) * 128 +
                                   ks * 32 + quad * 8);

  // stage x fp32 [c][n] -> fp16 [n][c]
  #pragma unroll
  for (int it = 0; it < 8; ++it) {
    int idx = it * 256 + tid;
    int f = (idx & 7) | ((idx >> 9) << 3);  // n-group 0..31
    int cp = (idx >> 3) & 63;               // c-pair 0..63
    const float* p0 = xb + (size_t)(2 * cp) * WLEN + n0 + 4 * f;
    float4 a = *(const float4*)p0;
    float4 c = *(const float4*)(p0 + WLEN);
    float av[4] = {a.x, a.y, a.z, a.w};
    float cv[4] = {c.x, c.y, c.z, c.w};
    #pragma unroll
    for (int i = 0; i < 4; ++i) {
      half2v h; h[0] = (_Float16)av[i]; h[1] = (_Float16)cv[i];
      *(half2v*)&xh[(4 * f + i) * 136 + 2 * cp] = h;
    }
  }
  __syncthreads();

  // phase 1: q_raw = Wq @ x : per wave M=32, N=128, K=128
  float4v acc[2][8] = {zero4, zero4, zero4, zero4, zero4, zero4, zero4, zero4,
                       zero4, zero4, zero4, zero4, zero4, zero4, zero4, zero4};
  #pragma unroll
  for (int ks = 0; ks < 4; ++ks) {
    half8 bf[8];
    #pragma unroll
    for (int nt = 0; nt < 8; ++nt)
      bf[nt] = *(const half8*)&xh[(nt * 16 + l15) * 136 + ks * 32 + quad * 8];
    #pragma unroll
    for (int mt = 0; mt < 2; ++mt)
      #pragma unroll
      for (int nt = 0; nt < 8; ++nt)
        acc[mt][nt] = MFMA16(a1[mt][ks], bf[nt], acc[mt][nt]);
  }
  // softmax over d (32 rows of this wave) per column, then * SCALE
  #pragma unroll
  for (int nt = 0; nt < 8; ++nt) {
    float mx = -1e30f;
    #pragma unroll
    for (int mt = 0; mt < 2; ++mt)
      #pragma unroll
      for (int r = 0; r < 4; ++r) mx = fmaxf(mx, acc[mt][nt][r]);
    mx = fmaxf(mx, __shfl_xor(mx, 16, 64));
    mx = fmaxf(mx, __shfl_xor(mx, 32, 64));
    float sm = 0.f;
    #pragma unroll
    for (int mt = 0; mt < 2; ++mt)
      #pragma unroll
      for (int r = 0; r < 4; ++r) {
        float e = __expf(acc[mt][nt][r] - mx);
        acc[mt][nt][r] = e;
        sm += e;
      }
    sm += __shfl_xor(sm, 16, 64);
    sm += __shfl_xor(sm, 32, 64);
    float sc = SCALEQ / sm;
    #pragma unroll
    for (int mt = 0; mt < 2; ++mt)
      #pragma unroll
      for (int r = 0; r < 4; ++r) acc[mt][nt][r] *= sc;
  }
  __syncthreads();  // all waves done reading xh as x
  // write q_sm -> q_l[n][hd] (same buffer)
  #pragma unroll
  for (int mt = 0; mt < 2; ++mt)
    #pragma unroll
    for (int nt = 0; nt < 8; ++nt) {
      half4 hq;
      #pragma unroll
      for (int r = 0; r < 4; ++r) hq[r] = (_Float16)acc[mt][nt][r];
      *(half4*)&xh[(nt * 16 + l15) * 136 + 32 * wv + mt * 16 + quad * 4] = hq;
    }
  __syncthreads();

  // phase 2: y = C_b @ q_sm : per wave M=32 (o-strip), N=128, K=128
  half8 a2[2][4];
  #pragma unroll
  for (int mt = 0; mt < 2; ++mt)
    #pragma unroll
    for (int ks = 0; ks < 4; ++ks)
      a2[mt][ks] = *(const half8*)(cb + (32 * wv + mt * 16 + l15) * 128 +
                                   ks * 32 + quad * 8);
  float4v acc2[2][8] = {zero4, zero4, zero4, zero4, zero4, zero4, zero4, zero4,
                        zero4, zero4, zero4, zero4, zero4, zero4, zero4, zero4};
  #pragma unroll
  for (int ks = 0; ks < 4; ++ks) {
    half8 bf[8];
    #pragma unroll
    for (int nt = 0; nt < 8; ++nt)
      bf[nt] = *(const half8*)&xh[(nt * 16 + l15) * 136 + ks * 32 + quad * 8];
    #pragma unroll
    for (int mt = 0; mt < 2; ++mt)
      #pragma unroll
      for (int nt = 0; nt < 8; ++nt)
        acc2[mt][nt] = MFMA16(a2[mt][ks], bf[nt], acc2[mt][nt]);
  }

  // epilogue: unscale, +b_out, LN stats
  float bo[8], ga[8], be[8];
  #pragma unroll
  for (int mt = 0; mt < 2; ++mt)
    #pragma unroll
    for (int r = 0; r < 4; ++r) {
      int o = 32 * wv + mt * 16 + quad * 4 + r;
      bo[mt * 4 + r] = b_out[o];
      ga[mt * 4 + r] = gamma[o];
      be[mt * 4 + r] = beta[o];
    }
  #pragma unroll
  for (int nt = 0; nt < 8; ++nt) {
    float ps = 0.f, pq = 0.f;
    #pragma unroll
    for (int mt = 0; mt < 2; ++mt)
      #pragma unroll
      for (int r = 0; r < 4; ++r) {
        float v = acc2[mt][nt][r] * CB_INV + bo[mt * 4 + r];
        acc2[mt][nt][r] = v;
        ps += v;
        pq += v * v;
      }
    ps += __shfl_xor(ps, 16, 64);
    ps += __shfl_xor(ps, 32, 64);
    pq += __shfl_xor(pq, 16, 64);
    pq += __shfl_xor(pq, 32, 64);
    if (quad == 0) {
      ssum[wv][nt * 16 + l15] = ps;
      ssq[wv][nt * 16 + l15] = pq;
    }
  }
  __syncthreads();
  if (tid < 128) {
    float s = ssum[0][tid] + ssum[1][tid] + ssum[2][tid] + ssum[3][tid];
    float q2 = ssq[0][tid] + ssq[1][tid] + ssq[2][tid] + ssq[3][tid];
    float mean = s * (1.0f / 128.0f);
    float var = q2 * (1.0f / 128.0f) - mean * mean;
    smean[tid] = mean;
    sinv[tid] = rsqrtf(var + 1e-5f);
  }
  __syncthreads();
  float* ob = out + (size_t)b * 128 * WLEN + n0;
  #pragma unroll
  for (int nt = 0; nt < 8; ++nt) {
    int n = nt * 16 + l15;
    float mean = smean[n], inv = sinv[n];
    #pragma unroll
    for (int mt = 0; mt < 2; ++mt)
      #pragma unroll
      for (int r = 0; r < 4; ++r) {
        int o = 32 * wv + mt * 16 + quad * 4 + r;
        ob[(size_t)o * WLEN + n] =
            (acc2[mt][nt][r] - mean) * inv * ga[mt * 4 + r] + be[mt * 4 + r];
      }
  }
}

extern "C" void kernel_launch(void* const* d_in, const int* in_sizes, int n_in,
                              void* d_out, int out_size, void* d_ws, size_t ws_size,
                              hipStream_t stream) {
  const float* x    = (const float*)d_in[0];
  const float* Wqkv = (const float*)d_in[1];
  const float* Wout = (const float*)d_in[2];
  const float* bo   = (const float*)d_in[3];
  const float* gam  = (const float*)d_in[4];
  const float* bet  = (const float*)d_in[5];
  float* out = (float*)d_out;
  float* ws  = (float*)d_ws;

  hipMemsetAsync(ws, 0, (65536 + 2048) * sizeof(float), stream);
  hipLaunchKernelGGL(k0_prep, dim3(192), dim3(256), 0, stream, Wqkv, ws);
  hipLaunchKernelGGL(ka_ctx, dim3(32, 16), dim3(256), 0, stream, x, ws);
  hipLaunchKernelGGL(kb_cb, dim3(16), dim3(256), 0, stream, Wout, ws);
  hipLaunchKernelGGL(kc_out, dim3(128, 16), dim3(256), 0, stream,
                     x, ws, bo, gam, bet, out);
}